// Round 7
// baseline (766.298 us; speedup 1.0000x reference)
//
#include <hip/hip_runtime.h>

// VQ-VAE quantize + EMA update, MI355X.
// R6: dist = hi/lo MFMA on B' = -2*embed (add3 epilogue, no launch_bounds cap —
//     R5's (256,2) regressed via spill);  scatter replaced by count(fused in dist)
//     -> scan -> reorder -> per-code reduce (no global atomics, no esum memset);
//     recheck tau=0.02.

#define N_ROWS 131072
#define DIM    64
#define NEMB   1024
#define FLAG_CAP 131072
#define TAU 0.02f

static constexpr float DECAYF = 0.99f;
static constexpr float OMDF   = (float)(1.0 - 0.99);
static constexpr float EPSF   = 1e-5f;
static constexpr float NEPSF  = (float)(1024 * 1e-5);

typedef __attribute__((ext_vector_type(8))) short short8;
typedef __attribute__((ext_vector_type(4))) float f32x4;

static __device__ __forceinline__ unsigned short f2bf(float f) {
    unsigned int u = __builtin_bit_cast(unsigned int, f);
    unsigned int r = (u + 0x7FFFu + ((u >> 16) & 1u)) >> 16;   // RNE
    return (unsigned short)r;
}
static __device__ __forceinline__ float bf2f(unsigned short h) {
    unsigned int u = ((unsigned int)h) << 16;
    return __builtin_bit_cast(float, u);
}

// ws layout (float offsets)
#define WS_CNT     0         // 1024 (int)
#define WS_DIFF    1024      // 1
#define WS_FLAGCNT 1025      // 1 (int)
#define WS_N       1026      // 1
#define WS_EE      1028      // 1024
#define WS_EMBEDT  2052      // 65536 (16B aligned: 2052*4 % 16 == 0)
#define WS_OFF     67588     // 1025 (int)
#define WS_CUR     68614     // 1024 (int)
#define WS_IDX     69640     // 131072 (int; 69640*4 % 16 == 0)
#define WS_FLAGLST 200712    // 131072 (int)
#define WS_SORTED  331784    // 131072 (int)
#define WS_ESUM    462856    // 65536
#define WS_BFRAG   528392    // 65536 floats = 256 KB (16B aligned)

// ---------------- prep: embedT, ee, hi/lo fragments of B' = -2*embed
// fid = ((ct*2 + kt)*2 + hl); lane holds B'[k=kt*32+(lane>>4)*8+j][col=ct*16+(lane&15)]
__global__ void prep_kernel(const float* __restrict__ embed,
                            float* __restrict__ embedT,
                            float* __restrict__ ee,
                            uint4* __restrict__ BfragG) {
    int tid = blockIdx.x * 256 + threadIdx.x;      // 0..16383
    for (int i = 0; i < 4; ++i) {
        int id = i * 16384 + tid;
        int d = id >> 10, e = id & 1023;
        embedT[e * 64 + d] = embed[id];
    }
    if (tid < NEMB) {
        float s = 0.f;
        for (int d = 0; d < DIM; ++d) {
            float v = embed[d * 1024 + tid];
            s = fmaf(v, v, s);
        }
        ee[tid] = s;
    }
    int fid  = tid >> 6;            // 0..255
    int lane = tid & 63;
    int hl = fid & 1, kt = (fid >> 1) & 1, ct = fid >> 2;
    int col = ct * 16 + (lane & 15);
    int k0  = kt * 32 + (lane >> 4) * 8;
    unsigned short u[8];
    #pragma unroll
    for (int j = 0; j < 8; ++j) {
        float v = -2.0f * embed[(k0 + j) * 1024 + col];
        unsigned short h = f2bf(v);
        if (hl) h = f2bf(v - bf2f(h));
        u[j] = h;
    }
    uint4 wv;
    wv.x = (unsigned)u[0] | ((unsigned)u[1] << 16);
    wv.y = (unsigned)u[2] | ((unsigned)u[3] << 16);
    wv.z = (unsigned)u[4] | ((unsigned)u[5] << 16);
    wv.w = (unsigned)u[6] | ((unsigned)u[7] << 16);
    BfragG[fid * 64 + lane] = wv;
}

// ---------------- dist: hi/lo MFMA + best2 + quantize + diff + counts
__global__ __launch_bounds__(256) void dist_kernel(
        const float* __restrict__ x, const uint4* __restrict__ BfragG,
        const float* __restrict__ ee, const float* __restrict__ embedT,
        float* __restrict__ out_q, float* __restrict__ out_ind,
        int* __restrict__ ws_idx, float* __restrict__ ws_diff,
        int* __restrict__ ws_flagcnt, int* __restrict__ ws_flaglist,
        int* __restrict__ ws_cnt) {
    __shared__ uint4 Bs[2048];            // 32 KB: one 128-col chunk (hi+lo frags)
    __shared__ int   sIdx[128];
    __shared__ float red[4];

    const int t = threadIdx.x;
    const int w = t >> 6, lane = t & 63;
    const int quad = lane >> 4, wl = lane & 15;
    const int rbase = blockIdx.x * 128;

    // A fragments (2 rowTiles x 2 kTiles, hi/lo), built once per block
    short8 a_hi[2][2], a_lo[2][2];
    #pragma unroll
    for (int rt = 0; rt < 2; ++rt) {
        int row = rbase + w * 32 + rt * 16 + wl;
        #pragma unroll
        for (int kt = 0; kt < 2; ++kt) {
            const float* px = x + (size_t)row * 64 + kt * 32 + quad * 8;
            float4 v0 = *(const float4*)px;
            float4 v1 = *(const float4*)(px + 4);
            float vv[8] = {v0.x, v0.y, v0.z, v0.w, v1.x, v1.y, v1.z, v1.w};
            short8 ah, al;
            #pragma unroll
            for (int j = 0; j < 8; ++j) {
                unsigned short h = f2bf(vv[j]);
                ah[j] = (short)h;
                al[j] = (short)f2bf(vv[j] - bf2f(h));
            }
            a_hi[rt][kt] = ah; a_lo[rt][kt] = al;
        }
    }

    float b1[8], b2[8];
    int   i1[8];
    #pragma unroll
    for (int s = 0; s < 8; ++s) { b1[s] = 3.4e38f; b2[s] = 3.4e38f; i1[s] = 0; }

    const f32x4 zacc = {0.f, 0.f, 0.f, 0.f};

    for (int ch = 0; ch < 8; ++ch) {
        __syncthreads();
        const uint4* src = BfragG + ch * 2048;
        #pragma unroll
        for (int it = 0; it < 8; ++it) Bs[it * 256 + t] = src[it * 256 + t];
        __syncthreads();

        #pragma unroll
        for (int ctl = 0; ctl < 8; ++ctl) {
            const short8* bp = (const short8*)Bs;
            short8 bh0 = bp[(ctl * 4 + 0) * 64 + lane];
            short8 bl0 = bp[(ctl * 4 + 1) * 64 + lane];
            short8 bh1 = bp[(ctl * 4 + 2) * 64 + lane];
            short8 bl1 = bp[(ctl * 4 + 3) * 64 + lane];
            int col = ch * 128 + ctl * 16 + wl;
            float eec = ee[col];
            #pragma unroll
            for (int rt = 0; rt < 2; ++rt) {
                // two independent 3-chains (one per k-tile); B already scaled by -2
                f32x4 c0 = __builtin_amdgcn_mfma_f32_16x16x32_bf16(a_lo[rt][0], bh0, zacc, 0, 0, 0);
                f32x4 c1 = __builtin_amdgcn_mfma_f32_16x16x32_bf16(a_lo[rt][1], bh1, zacc, 0, 0, 0);
                c0 = __builtin_amdgcn_mfma_f32_16x16x32_bf16(a_hi[rt][0], bl0, c0, 0, 0, 0);
                c1 = __builtin_amdgcn_mfma_f32_16x16x32_bf16(a_hi[rt][1], bl1, c1, 0, 0, 0);
                c0 = __builtin_amdgcn_mfma_f32_16x16x32_bf16(a_hi[rt][0], bh0, c0, 0, 0, 0);
                c1 = __builtin_amdgcn_mfma_f32_16x16x32_bf16(a_hi[rt][1], bh1, c1, 0, 0, 0);
                #pragma unroll
                for (int reg = 0; reg < 4; ++reg) {
                    float s = c0[reg] + c1[reg] + eec;          // v_add3_f32
                    int st = rt * 4 + reg;
                    bool lt = s < b1[st];
                    b2[st] = fminf(fmaxf(s, b1[st]), b2[st]);   // streaming 2nd-min
                    i1[st] = lt ? col : i1[st];
                    b1[st] = fminf(s, b1[st]);
                }
            }
        }
    }

    // merge across 16 column-lanes
    for (int m = 1; m < 16; m <<= 1) {
        #pragma unroll
        for (int s = 0; s < 8; ++s) {
            float ob1 = __shfl_xor(b1[s], m);
            int   oi1 = __shfl_xor(i1[s], m);
            float ob2 = __shfl_xor(b2[s], m);
            if (ob1 < b1[s] || (ob1 == b1[s] && oi1 < i1[s])) {
                b2[s] = fminf(b1[s], ob2); b1[s] = ob1; i1[s] = oi1;
            } else {
                b2[s] = fminf(b2[s], ob1);
            }
        }
    }
    if (wl == 0) {
        #pragma unroll
        for (int s = 0; s < 8; ++s) {
            int rt = s >> 2, reg = s & 3;
            int rloc = w * 32 + rt * 16 + quad * 4 + reg;
            int row = rbase + rloc;
            sIdx[rloc] = i1[s];
            ws_idx[row] = i1[s];
            out_ind[row] = (float)i1[s];
            if (b2[s] - b1[s] < TAU) {
                int pos = atomicAdd(ws_flagcnt, 1);
                if (pos < FLAG_CAP) ws_flaglist[pos] = row;
            }
        }
    }
    __syncthreads();

    // cluster-size counts (recheck patches if idx changes)
    if (t < 128) atomicAdd(&ws_cnt[sIdx[t]], 1);

    // quantize + straight-through + diff partial
    {
        int r = t >> 1, hh = t & 1;
        int e = sIdx[r];
        const float4* et = (const float4*)(embedT + e * 64 + hh * 32);
        const float4* xr = (const float4*)(x + (size_t)(rbase + r) * 64 + hh * 32);
        float4*       qo = (float4*)(out_q + (size_t)(rbase + r) * 64 + hh * 32);
        float dsum = 0.f;
        #pragma unroll
        for (int v = 0; v < 8; ++v) {
            float4 q4 = et[v];
            float4 x4 = xr[v];
            float dx = q4.x - x4.x, dy = q4.y - x4.y, dz = q4.z - x4.z, dw = q4.w - x4.w;
            float4 o;
            o.x = x4.x + dx; o.y = x4.y + dy; o.z = x4.z + dz; o.w = x4.w + dw;
            qo[v] = o;
            dsum += dx * dx + dy * dy + dz * dz + dw * dw;
        }
        for (int o2 = 32; o2 > 0; o2 >>= 1) dsum += __shfl_down(dsum, o2);
        if (lane == 0) red[w] = dsum;
        __syncthreads();
        if (t == 0) atomicAdd(ws_diff, red[0] + red[1] + red[2] + red[3]);
    }
}

// ---------------- recheck: tiled exact fp32 re-argmin (8 rows/tile)
__global__ __launch_bounds__(256) void recheck_kernel(
        const float* __restrict__ x, const float* __restrict__ embed,
        const float* __restrict__ embedT, const float* __restrict__ ee,
        const int* __restrict__ flagcnt, const int* __restrict__ flaglist,
        int* __restrict__ ws_idx, float* __restrict__ out_ind,
        float* __restrict__ out_q, float* __restrict__ ws_diff,
        int* __restrict__ ws_cnt) {
    __shared__ float sx[8][64];
    __shared__ float sff[8];
    __shared__ int   srow[8];
    __shared__ float sbd[256];
    __shared__ int   sbi[256];
    __shared__ int   schg[2];
    int t = threadIdx.x;
    int cnt = *flagcnt;
    if (cnt > FLAG_CAP) cnt = FLAG_CAP;
    int ntiles = (cnt + 7) >> 3;
    for (int tile = blockIdx.x; tile < ntiles; tile += gridDim.x) {
        int base = tile * 8;
        int nr = cnt - base; if (nr > 8) nr = 8;
        __syncthreads();
        if (t < nr) srow[t] = flaglist[base + t];
        __syncthreads();
        for (int l = t; l < nr * 64; l += 256)
            sx[l >> 6][l & 63] = x[(size_t)srow[l >> 6] * 64 + (l & 63)];
        __syncthreads();
        if (t < nr) {
            float ff = 0.f;
            for (int k = 0; k < 64; ++k) ff = fmaf(sx[t][k], sx[t][k], ff);
            sff[t] = ff;
        }
        float acc[8][4];
        #pragma unroll
        for (int r = 0; r < 8; ++r)
            #pragma unroll
            for (int j = 0; j < 4; ++j) acc[r][j] = 0.f;
        int c0 = t * 4;
        for (int k = 0; k < 64; ++k) {
            float4 e4 = *(const float4*)(embed + k * 1024 + c0);
            #pragma unroll
            for (int r = 0; r < 8; ++r) {
                float xk = sx[r][k];
                acc[r][0] = fmaf(xk, e4.x, acc[r][0]);
                acc[r][1] = fmaf(xk, e4.y, acc[r][1]);
                acc[r][2] = fmaf(xk, e4.z, acc[r][2]);
                acc[r][3] = fmaf(xk, e4.w, acc[r][3]);
            }
        }
        __syncthreads();
        for (int r = 0; r < nr; ++r) {
            int row = srow[r];
            float ff = sff[r];
            float bd = 3.4e38f; int bi = 0;
            #pragma unroll
            for (int j = 0; j < 4; ++j) {
                float d = (ff - 2.f * acc[r][j]) + ee[c0 + j];
                if (d < bd) { bd = d; bi = c0 + j; }
            }
            sbd[t] = bd; sbi[t] = bi;
            __syncthreads();
            for (int s = 128; s > 0; s >>= 1) {
                if (t < s) {
                    float od = sbd[t + s]; int oi = sbi[t + s];
                    if (od < sbd[t] || (od == sbd[t] && oi < sbi[t])) { sbd[t] = od; sbi[t] = oi; }
                }
                __syncthreads();
            }
            if (t == 0) {
                int ni = sbi[0], oi = ws_idx[row];
                schg[0] = ni; schg[1] = oi;
                if (ni != oi) {
                    ws_idx[row] = ni; out_ind[row] = (float)ni;
                    atomicAdd(&ws_cnt[oi], -1);
                    atomicAdd(&ws_cnt[ni], 1);
                }
            }
            __syncthreads();
            int ni = schg[0], oi = schg[1];
            if (ni != oi && t < 64) {
                float xv = sx[r][t];
                float dn = embedT[ni * 64 + t] - xv;
                float dold = embedT[oi * 64 + t] - xv;
                out_q[(size_t)row * 64 + t] = xv + dn;
                float delta = dn * dn - dold * dold;
                for (int o = 32; o > 0; o >>= 1) delta += __shfl_down(delta, o);
                if (t == 0) atomicAdd(ws_diff, delta);
            }
            __syncthreads();
        }
    }
}

// ---------------- scan: exclusive prefix of counts + new_cluster_size + n + diff
__global__ __launch_bounds__(1024) void scan_kernel(
        const float* __restrict__ cluster_size, const int* __restrict__ ws_cnt,
        const float* __restrict__ ws_diff, float* __restrict__ out_diff,
        float* __restrict__ out_ncs, float* __restrict__ ws_n,
        int* __restrict__ ws_off, int* __restrict__ ws_cur) {
    __shared__ int s[1024];
    __shared__ float sred[16];
    int t = threadIdx.x;
    int c = ws_cnt[t];
    s[t] = c;
    __syncthreads();
    for (int o = 1; o < 1024; o <<= 1) {
        int v = (t >= o) ? s[t - o] : 0;
        __syncthreads();
        s[t] += v;
        __syncthreads();
    }
    int excl = s[t] - c;
    ws_off[t] = excl;
    ws_cur[t] = excl;
    if (t == 1023) ws_off[1024] = s[1023];

    float ncs = DECAYF * cluster_size[t] + OMDF * (float)c;
    out_ncs[t] = ncs;
    float v = ncs;
    for (int o = 32; o > 0; o >>= 1) v += __shfl_down(v, o);
    if ((t & 63) == 0) sred[t >> 6] = v;
    __syncthreads();
    if (t == 0) {
        float n = 0.f;
        for (int i = 0; i < 16; ++i) n += sred[i];
        ws_n[0] = n;
        out_diff[0] = ws_diff[0] * (1.0f / 8388608.0f);   // /2^23 exact
    }
}

// ---------------- reorder: code-sorted row list
__global__ __launch_bounds__(256) void reorder_kernel(
        const int* __restrict__ ws_idx, int* __restrict__ ws_cur,
        int* __restrict__ ws_sorted) {
    int i = blockIdx.x * 256 + threadIdx.x;     // 512 blocks -> 131072
    int e = ws_idx[i];
    int pos = atomicAdd(&ws_cur[e], 1);
    ws_sorted[pos] = i;
}

// ---------------- reduce: per-code feature sum from sorted rows (no atomics)
__global__ __launch_bounds__(256) void reduce_kernel(
        const int* __restrict__ ws_off, const int* __restrict__ ws_sorted,
        const float* __restrict__ x, float* __restrict__ esum) {
    __shared__ float sacc[4][64];
    const int e = blockIdx.x;
    const int w = threadIdx.x >> 6, lane = threadIdx.x & 63;
    const int start = ws_off[e], end = ws_off[e + 1];
    float acc = 0.f;
    int j = start + w;
    int row_next = (j < end) ? ws_sorted[j] : -1;
    while (row_next >= 0) {
        int row = row_next;
        j += 4;
        row_next = (j < end) ? ws_sorted[j] : -1;
        acc += x[(size_t)row * 64 + lane];
    }
    sacc[w][lane] = acc;
    __syncthreads();
    if (threadIdx.x < 64) {
        int d = threadIdx.x;
        esum[d * 1024 + e] = sacc[0][d] + sacc[1][d] + sacc[2][d] + sacc[3][d];
    }
}

// ---------------- finalize2: new_embed_avg, new_embed
__global__ __launch_bounds__(256) void finalize2(
        const float* __restrict__ embed_avg, const float* __restrict__ esum,
        const float* __restrict__ out_ncs, const float* __restrict__ ws_n,
        float* __restrict__ out_nea, float* __restrict__ out_ne) {
    int i = blockIdx.x * 256 + threadIdx.x;
    float n = ws_n[0];
    float nea = DECAYF * embed_avg[i] + OMDF * esum[i];
    out_nea[i] = nea;
    float ncs = out_ncs[i & 1023];
    float cs = (ncs + EPSF) / (n + NEPSF) * n;
    out_ne[i] = nea / cs;
}

extern "C" void kernel_launch(void* const* d_in, const int* in_sizes, int n_in,
                              void* d_out, int out_size, void* d_ws, size_t ws_size,
                              hipStream_t stream) {
    const float* x            = (const float*)d_in[0];
    const float* embed        = (const float*)d_in[1];
    const float* cluster_size = (const float*)d_in[2];
    const float* embed_avg    = (const float*)d_in[3];

    float* out = (float*)d_out;
    float* out_q    = out;                       // 8388608
    float* out_diff = out + 8388608;             // 1
    float* out_ind  = out + 8388609;             // 131072
    float* out_ncs  = out + 8519681;             // 1024
    float* out_nea  = out + 8520705;             // 65536
    float* out_ne   = out + 8586241;             // 65536

    float* ws = (float*)d_ws;
    int*   ws_cnt      = (int*)(ws + WS_CNT);
    float* ws_diff     = ws + WS_DIFF;
    int*   ws_flagcnt  = (int*)(ws + WS_FLAGCNT);
    float* ws_n        = ws + WS_N;
    float* ws_ee       = ws + WS_EE;
    float* ws_embedT   = ws + WS_EMBEDT;
    int*   ws_off      = (int*)(ws + WS_OFF);
    int*   ws_cur      = (int*)(ws + WS_CUR);
    int*   ws_idx      = (int*)(ws + WS_IDX);
    int*   ws_flaglist = (int*)(ws + WS_FLAGLST);
    int*   ws_sorted   = (int*)(ws + WS_SORTED);
    float* ws_esum     = ws + WS_ESUM;
    uint4* ws_Bfrag    = (uint4*)(ws + WS_BFRAG);

    // zero cnt + diff + flagcnt (contiguous at base)
    hipMemsetAsync(d_ws, 0, (size_t)(WS_FLAGCNT + 1) * 4, stream);

    prep_kernel<<<64, 256, 0, stream>>>(embed, ws_embedT, ws_ee, ws_Bfrag);
    dist_kernel<<<N_ROWS / 128, 256, 0, stream>>>(x, ws_Bfrag, ws_ee, ws_embedT,
                                                  out_q, out_ind, ws_idx, ws_diff,
                                                  ws_flagcnt, ws_flaglist, ws_cnt);
    recheck_kernel<<<256, 256, 0, stream>>>(x, embed, ws_embedT, ws_ee,
                                            ws_flagcnt, ws_flaglist,
                                            ws_idx, out_ind, out_q, ws_diff, ws_cnt);
    scan_kernel<<<1, 1024, 0, stream>>>(cluster_size, ws_cnt, ws_diff,
                                        out_diff, out_ncs, ws_n, ws_off, ws_cur);
    reorder_kernel<<<N_ROWS / 256, 256, 0, stream>>>(ws_idx, ws_cur, ws_sorted);
    reduce_kernel<<<NEMB, 256, 0, stream>>>(ws_off, ws_sorted, x, ws_esum);
    finalize2<<<256, 256, 0, stream>>>(embed_avg, ws_esum, out_ncs, ws_n,
                                       out_nea, out_ne);
}

// Round 8
// 318.916 us; speedup vs baseline: 2.4028x; 2.4028x over previous
//
#include <hip/hip_runtime.h>

// VQ-VAE quantize + EMA update, MI355X.
// R7: scatter = skew-immune LDS histogram (64 ranges x 8 dim-octants, 32KB hist
//     + fused counts in octant-0), replacing R6's sort/reduce (424us: load
//     imbalance — hot code serialized one block). Counts removed from dist.
//     dist/recheck = R6 structure (hi/lo MFMA on B'=-2E, tau=0.02).

#define N_ROWS 131072
#define DIM    64
#define NEMB   1024
#define FLAG_CAP 131072
#define TAU 0.02f

static constexpr float DECAYF = 0.99f;
static constexpr float OMDF   = (float)(1.0 - 0.99);
static constexpr float EPSF   = 1e-5f;
static constexpr float NEPSF  = (float)(1024 * 1e-5);

typedef __attribute__((ext_vector_type(8))) short short8;
typedef __attribute__((ext_vector_type(4))) float f32x4;

static __device__ __forceinline__ unsigned short f2bf(float f) {
    unsigned int u = __builtin_bit_cast(unsigned int, f);
    unsigned int r = (u + 0x7FFFu + ((u >> 16) & 1u)) >> 16;   // RNE
    return (unsigned short)r;
}
static __device__ __forceinline__ float bf2f(unsigned short h) {
    unsigned int u = ((unsigned int)h) << 16;
    return __builtin_bit_cast(float, u);
}

// ws layout (float offsets)
#define WS_ESUM    0         // 65536
#define WS_CNTF    65536     // 1024
#define WS_DIFF    66560     // 1
#define WS_FLAGCNT 66561     // 1 (int)
#define WS_N       66562     // 1
#define WS_EE      66564     // 1024
#define WS_EMBEDT  67588     // 65536
#define WS_IDX     133124    // 131072 (int)
#define WS_FLAGLST 264196    // 131072 (int)
#define WS_BFRAG   395268    // 65536 floats = 256 KB (16B aligned)

// ---------------- prep: embedT, ee, hi/lo fragments of B' = -2*embed
__global__ void prep_kernel(const float* __restrict__ embed,
                            float* __restrict__ embedT,
                            float* __restrict__ ee,
                            uint4* __restrict__ BfragG) {
    int tid = blockIdx.x * 256 + threadIdx.x;      // 0..16383
    for (int i = 0; i < 4; ++i) {
        int id = i * 16384 + tid;
        int d = id >> 10, e = id & 1023;
        embedT[e * 64 + d] = embed[id];
    }
    if (tid < NEMB) {
        float s = 0.f;
        for (int d = 0; d < DIM; ++d) {
            float v = embed[d * 1024 + tid];
            s = fmaf(v, v, s);
        }
        ee[tid] = s;
    }
    int fid  = tid >> 6;            // 0..255
    int lane = tid & 63;
    int hl = fid & 1, kt = (fid >> 1) & 1, ct = fid >> 2;
    int col = ct * 16 + (lane & 15);
    int k0  = kt * 32 + (lane >> 4) * 8;
    unsigned short u[8];
    #pragma unroll
    for (int j = 0; j < 8; ++j) {
        float v = -2.0f * embed[(k0 + j) * 1024 + col];
        unsigned short h = f2bf(v);
        if (hl) h = f2bf(v - bf2f(h));
        u[j] = h;
    }
    uint4 wv;
    wv.x = (unsigned)u[0] | ((unsigned)u[1] << 16);
    wv.y = (unsigned)u[2] | ((unsigned)u[3] << 16);
    wv.z = (unsigned)u[4] | ((unsigned)u[5] << 16);
    wv.w = (unsigned)u[6] | ((unsigned)u[7] << 16);
    BfragG[fid * 64 + lane] = wv;
}

// ---------------- dist: hi/lo MFMA + best2 + quantize + diff
__global__ __launch_bounds__(256) void dist_kernel(
        const float* __restrict__ x, const uint4* __restrict__ BfragG,
        const float* __restrict__ ee, const float* __restrict__ embedT,
        float* __restrict__ out_q, float* __restrict__ out_ind,
        int* __restrict__ ws_idx, float* __restrict__ ws_diff,
        int* __restrict__ ws_flagcnt, int* __restrict__ ws_flaglist) {
    __shared__ uint4 Bs[2048];            // 32 KB: one 128-col chunk (hi+lo frags)
    __shared__ int   sIdx[128];
    __shared__ float red[4];

    const int t = threadIdx.x;
    const int w = t >> 6, lane = t & 63;
    const int quad = lane >> 4, wl = lane & 15;
    const int rbase = blockIdx.x * 128;

    short8 a_hi[2][2], a_lo[2][2];
    #pragma unroll
    for (int rt = 0; rt < 2; ++rt) {
        int row = rbase + w * 32 + rt * 16 + wl;
        #pragma unroll
        for (int kt = 0; kt < 2; ++kt) {
            const float* px = x + (size_t)row * 64 + kt * 32 + quad * 8;
            float4 v0 = *(const float4*)px;
            float4 v1 = *(const float4*)(px + 4);
            float vv[8] = {v0.x, v0.y, v0.z, v0.w, v1.x, v1.y, v1.z, v1.w};
            short8 ah, al;
            #pragma unroll
            for (int j = 0; j < 8; ++j) {
                unsigned short h = f2bf(vv[j]);
                ah[j] = (short)h;
                al[j] = (short)f2bf(vv[j] - bf2f(h));
            }
            a_hi[rt][kt] = ah; a_lo[rt][kt] = al;
        }
    }

    float b1[8], b2[8];
    int   i1[8];
    #pragma unroll
    for (int s = 0; s < 8; ++s) { b1[s] = 3.4e38f; b2[s] = 3.4e38f; i1[s] = 0; }

    const f32x4 zacc = {0.f, 0.f, 0.f, 0.f};

    for (int ch = 0; ch < 8; ++ch) {
        __syncthreads();
        const uint4* src = BfragG + ch * 2048;
        #pragma unroll
        for (int it = 0; it < 8; ++it) Bs[it * 256 + t] = src[it * 256 + t];
        __syncthreads();

        #pragma unroll
        for (int ctl = 0; ctl < 8; ++ctl) {
            const short8* bp = (const short8*)Bs;
            short8 bh0 = bp[(ctl * 4 + 0) * 64 + lane];
            short8 bl0 = bp[(ctl * 4 + 1) * 64 + lane];
            short8 bh1 = bp[(ctl * 4 + 2) * 64 + lane];
            short8 bl1 = bp[(ctl * 4 + 3) * 64 + lane];
            int col = ch * 128 + ctl * 16 + wl;
            float eec = ee[col];
            #pragma unroll
            for (int rt = 0; rt < 2; ++rt) {
                f32x4 c0 = __builtin_amdgcn_mfma_f32_16x16x32_bf16(a_lo[rt][0], bh0, zacc, 0, 0, 0);
                f32x4 c1 = __builtin_amdgcn_mfma_f32_16x16x32_bf16(a_lo[rt][1], bh1, zacc, 0, 0, 0);
                c0 = __builtin_amdgcn_mfma_f32_16x16x32_bf16(a_hi[rt][0], bl0, c0, 0, 0, 0);
                c1 = __builtin_amdgcn_mfma_f32_16x16x32_bf16(a_hi[rt][1], bl1, c1, 0, 0, 0);
                c0 = __builtin_amdgcn_mfma_f32_16x16x32_bf16(a_hi[rt][0], bh0, c0, 0, 0, 0);
                c1 = __builtin_amdgcn_mfma_f32_16x16x32_bf16(a_hi[rt][1], bh1, c1, 0, 0, 0);
                #pragma unroll
                for (int reg = 0; reg < 4; ++reg) {
                    float s = c0[reg] + c1[reg] + eec;          // v_add3_f32
                    int st = rt * 4 + reg;
                    bool lt = s < b1[st];
                    b2[st] = fminf(fmaxf(s, b1[st]), b2[st]);
                    i1[st] = lt ? col : i1[st];
                    b1[st] = fminf(s, b1[st]);
                }
            }
        }
    }

    for (int m = 1; m < 16; m <<= 1) {
        #pragma unroll
        for (int s = 0; s < 8; ++s) {
            float ob1 = __shfl_xor(b1[s], m);
            int   oi1 = __shfl_xor(i1[s], m);
            float ob2 = __shfl_xor(b2[s], m);
            if (ob1 < b1[s] || (ob1 == b1[s] && oi1 < i1[s])) {
                b2[s] = fminf(b1[s], ob2); b1[s] = ob1; i1[s] = oi1;
            } else {
                b2[s] = fminf(b2[s], ob1);
            }
        }
    }
    if (wl == 0) {
        #pragma unroll
        for (int s = 0; s < 8; ++s) {
            int rt = s >> 2, reg = s & 3;
            int rloc = w * 32 + rt * 16 + quad * 4 + reg;
            int row = rbase + rloc;
            sIdx[rloc] = i1[s];
            ws_idx[row] = i1[s];
            out_ind[row] = (float)i1[s];
            if (b2[s] - b1[s] < TAU) {
                int pos = atomicAdd(ws_flagcnt, 1);
                if (pos < FLAG_CAP) ws_flaglist[pos] = row;
            }
        }
    }
    __syncthreads();

    // quantize + straight-through + diff partial
    {
        int r = t >> 1, hh = t & 1;
        int e = sIdx[r];
        const float4* et = (const float4*)(embedT + e * 64 + hh * 32);
        const float4* xr = (const float4*)(x + (size_t)(rbase + r) * 64 + hh * 32);
        float4*       qo = (float4*)(out_q + (size_t)(rbase + r) * 64 + hh * 32);
        float dsum = 0.f;
        #pragma unroll
        for (int v = 0; v < 8; ++v) {
            float4 q4 = et[v];
            float4 x4 = xr[v];
            float dx = q4.x - x4.x, dy = q4.y - x4.y, dz = q4.z - x4.z, dw = q4.w - x4.w;
            float4 o;
            o.x = x4.x + dx; o.y = x4.y + dy; o.z = x4.z + dz; o.w = x4.w + dw;
            qo[v] = o;
            dsum += dx * dx + dy * dy + dz * dz + dw * dw;
        }
        for (int o2 = 32; o2 > 0; o2 >>= 1) dsum += __shfl_down(dsum, o2);
        if (lane == 0) red[w] = dsum;
        __syncthreads();
        if (t == 0) atomicAdd(ws_diff, red[0] + red[1] + red[2] + red[3]);
    }
}

// ---------------- recheck: tiled exact fp32 re-argmin (8 rows/tile)
__global__ __launch_bounds__(256) void recheck_kernel(
        const float* __restrict__ x, const float* __restrict__ embed,
        const float* __restrict__ embedT, const float* __restrict__ ee,
        const int* __restrict__ flagcnt, const int* __restrict__ flaglist,
        int* __restrict__ ws_idx, float* __restrict__ out_ind,
        float* __restrict__ out_q, float* __restrict__ ws_diff) {
    __shared__ float sx[8][64];
    __shared__ float sff[8];
    __shared__ int   srow[8];
    __shared__ float sbd[256];
    __shared__ int   sbi[256];
    __shared__ int   schg[2];
    int t = threadIdx.x;
    int cnt = *flagcnt;
    if (cnt > FLAG_CAP) cnt = FLAG_CAP;
    int ntiles = (cnt + 7) >> 3;
    for (int tile = blockIdx.x; tile < ntiles; tile += gridDim.x) {
        int base = tile * 8;
        int nr = cnt - base; if (nr > 8) nr = 8;
        __syncthreads();
        if (t < nr) srow[t] = flaglist[base + t];
        __syncthreads();
        for (int l = t; l < nr * 64; l += 256)
            sx[l >> 6][l & 63] = x[(size_t)srow[l >> 6] * 64 + (l & 63)];
        __syncthreads();
        if (t < nr) {
            float ff = 0.f;
            for (int k = 0; k < 64; ++k) ff = fmaf(sx[t][k], sx[t][k], ff);
            sff[t] = ff;
        }
        float acc[8][4];
        #pragma unroll
        for (int r = 0; r < 8; ++r)
            #pragma unroll
            for (int j = 0; j < 4; ++j) acc[r][j] = 0.f;
        int c0 = t * 4;
        for (int k = 0; k < 64; ++k) {
            float4 e4 = *(const float4*)(embed + k * 1024 + c0);
            #pragma unroll
            for (int r = 0; r < 8; ++r) {
                float xk = sx[r][k];
                acc[r][0] = fmaf(xk, e4.x, acc[r][0]);
                acc[r][1] = fmaf(xk, e4.y, acc[r][1]);
                acc[r][2] = fmaf(xk, e4.z, acc[r][2]);
                acc[r][3] = fmaf(xk, e4.w, acc[r][3]);
            }
        }
        __syncthreads();
        for (int r = 0; r < nr; ++r) {
            int row = srow[r];
            float ff = sff[r];
            float bd = 3.4e38f; int bi = 0;
            #pragma unroll
            for (int j = 0; j < 4; ++j) {
                float d = (ff - 2.f * acc[r][j]) + ee[c0 + j];
                if (d < bd) { bd = d; bi = c0 + j; }
            }
            sbd[t] = bd; sbi[t] = bi;
            __syncthreads();
            for (int s = 128; s > 0; s >>= 1) {
                if (t < s) {
                    float od = sbd[t + s]; int oi = sbi[t + s];
                    if (od < sbd[t] || (od == sbd[t] && oi < sbi[t])) { sbd[t] = od; sbi[t] = oi; }
                }
                __syncthreads();
            }
            if (t == 0) {
                int ni = sbi[0], oi = ws_idx[row];
                schg[0] = ni; schg[1] = oi;
                if (ni != oi) { ws_idx[row] = ni; out_ind[row] = (float)ni; }
            }
            __syncthreads();
            int ni = schg[0], oi = schg[1];
            if (ni != oi && t < 64) {
                float xv = sx[r][t];
                float dn = embedT[ni * 64 + t] - xv;
                float dold = embedT[oi * 64 + t] - xv;
                out_q[(size_t)row * 64 + t] = xv + dn;
                float delta = dn * dn - dold * dold;
                for (int o = 32; o > 0; o >>= 1) delta += __shfl_down(delta, o);
                if (t == 0) atomicAdd(ws_diff, delta);
            }
            __syncthreads();
        }
    }
}

// ---------------- scatter: 128 row-ranges x 8 dim-octants; 32KB LDS histogram
// octant-0 blocks also build the count histogram. Skew-immune: fixed row range
// per block, LDS atomics, <=1 global atomic per (code,dim) per block.
__global__ __launch_bounds__(256) void scatter_kernel(
        const int* __restrict__ idx, const float* __restrict__ x,
        float* __restrict__ esum, float* __restrict__ cntf) {
    __shared__ float shist[8192];         // [1024 codes][8 dims] = 32 KB
    __shared__ float scnt[1024];          // used by oct==0 blocks
    const int t = threadIdx.x;
    const int range = blockIdx.x >> 3, oct = blockIdx.x & 7;   // 128 ranges x 8
    const int w = t >> 6, lane = t & 63;
    const int g = lane >> 3, d = lane & 7;                      // 8 rows x 8 dims

    for (int i = t; i < 8192; i += 256) shist[i] = 0.f;
    if (oct == 0) for (int i = t; i < 1024; i += 256) scnt[i] = 0.f;
    __syncthreads();

    const int row0 = range * 1024 + w * 256;
    for (int it = 0; it < 32; ++it) {                 // 32 x 8 rows per wave
        int row = row0 + it * 8 + g;
        int e = idx[row];
        float xv = x[(size_t)row * 64 + oct * 8 + d];
        atomicAdd(&shist[e * 8 + d], xv);
        if (oct == 0 && d == 0) atomicAdd(&scnt[e], 1.0f);
    }
    __syncthreads();

    for (int cell = t; cell < 8192; cell += 256) {
        float v = shist[cell];
        if (v != 0.f)
            atomicAdd(&esum[(oct * 8 + (cell & 7)) * 1024 + (cell >> 3)], v);
    }
    if (oct == 0) {
        for (int i = t; i < 1024; i += 256) {
            float c = scnt[i];
            if (c != 0.f) atomicAdd(&cntf[i], c);
        }
    }
}

// ---------------- finalize1: new_cluster_size, n, diff
__global__ __launch_bounds__(1024) void finalize1(
        const float* __restrict__ cluster_size, const float* __restrict__ cntf,
        const float* __restrict__ ws_diff, float* __restrict__ out_diff,
        float* __restrict__ out_ncs, float* __restrict__ ws_n) {
    int t = threadIdx.x;
    float ncs = DECAYF * cluster_size[t] + OMDF * cntf[t];
    out_ncs[t] = ncs;
    __shared__ float sred[16];
    float v = ncs;
    for (int o = 32; o > 0; o >>= 1) v += __shfl_down(v, o);
    if ((t & 63) == 0) sred[t >> 6] = v;
    __syncthreads();
    if (t == 0) {
        float n = 0.f;
        for (int i = 0; i < 16; ++i) n += sred[i];
        ws_n[0] = n;
        out_diff[0] = ws_diff[0] * (1.0f / 8388608.0f);   // /2^23 exact
    }
}

// ---------------- finalize2: new_embed_avg, new_embed
__global__ __launch_bounds__(256) void finalize2(
        const float* __restrict__ embed_avg, const float* __restrict__ esum,
        const float* __restrict__ out_ncs, const float* __restrict__ ws_n,
        float* __restrict__ out_nea, float* __restrict__ out_ne) {
    int i = blockIdx.x * 256 + threadIdx.x;
    float n = ws_n[0];
    float nea = DECAYF * embed_avg[i] + OMDF * esum[i];
    out_nea[i] = nea;
    float ncs = out_ncs[i & 1023];
    float cs = (ncs + EPSF) / (n + NEPSF) * n;
    out_ne[i] = nea / cs;
}

extern "C" void kernel_launch(void* const* d_in, const int* in_sizes, int n_in,
                              void* d_out, int out_size, void* d_ws, size_t ws_size,
                              hipStream_t stream) {
    const float* x            = (const float*)d_in[0];
    const float* embed        = (const float*)d_in[1];
    const float* cluster_size = (const float*)d_in[2];
    const float* embed_avg    = (const float*)d_in[3];

    float* out = (float*)d_out;
    float* out_q    = out;                       // 8388608
    float* out_diff = out + 8388608;             // 1
    float* out_ind  = out + 8388609;             // 131072
    float* out_ncs  = out + 8519681;             // 1024
    float* out_nea  = out + 8520705;             // 65536
    float* out_ne   = out + 8586241;             // 65536

    float* ws = (float*)d_ws;
    float* ws_esum     = ws + WS_ESUM;
    float* ws_cntf     = ws + WS_CNTF;
    float* ws_diff     = ws + WS_DIFF;
    int*   ws_flagcnt  = (int*)(ws + WS_FLAGCNT);
    float* ws_n        = ws + WS_N;
    float* ws_ee       = ws + WS_EE;
    float* ws_embedT   = ws + WS_EMBEDT;
    int*   ws_idx      = (int*)(ws + WS_IDX);
    int*   ws_flaglist = (int*)(ws + WS_FLAGLST);
    uint4* ws_Bfrag    = (uint4*)(ws + WS_BFRAG);

    // zero esum + cntf + diff + flagcnt (contiguous at base, 266 KB)
    hipMemsetAsync(d_ws, 0, (size_t)(WS_FLAGCNT + 1) * 4, stream);

    prep_kernel<<<64, 256, 0, stream>>>(embed, ws_embedT, ws_ee, ws_Bfrag);
    dist_kernel<<<N_ROWS / 128, 256, 0, stream>>>(x, ws_Bfrag, ws_ee, ws_embedT,
                                                  out_q, out_ind, ws_idx, ws_diff,
                                                  ws_flagcnt, ws_flaglist);
    recheck_kernel<<<256, 256, 0, stream>>>(x, embed, ws_embedT, ws_ee,
                                            ws_flagcnt, ws_flaglist,
                                            ws_idx, out_ind, out_q, ws_diff);
    scatter_kernel<<<1024, 256, 0, stream>>>(ws_idx, x, ws_esum, ws_cntf);
    finalize1<<<1, 1024, 0, stream>>>(cluster_size, ws_cntf, ws_diff,
                                      out_diff, out_ncs, ws_n);
    finalize2<<<256, 256, 0, stream>>>(embed_avg, ws_esum, out_ncs, ws_n,
                                       out_nea, out_ne);
}

// Round 9
// 285.124 us; speedup vs baseline: 2.6876x; 1.1185x over previous
//
#include <hip/hip_runtime.h>

// VQ-VAE quantize + EMA update, MI355X.
// R8: scatter flush rewritten — R7 did ~8.4M global fp32 atomics (1024 blocks x
//     8192 cells, 128-way contention) ≈ the hidden ~150us. Now: 256 blocks
//     (32 ranges x 8 octants) write per-block partials (plain coalesced stores,
//     zero global atomics); finalize2 fuses the 32-slab reduction. idx/x
//     prefetch breaks the dependent-load chain. Runtime ws_size guard falls
//     back to atomic path. dist/recheck unchanged from R7 (115us, no spill).

#define N_ROWS 131072
#define DIM    64
#define NEMB   1024
#define FLAG_CAP 131072
#define TAU 0.02f
#define NRANGE 32

static constexpr float DECAYF = 0.99f;
static constexpr float OMDF   = (float)(1.0 - 0.99);
static constexpr float EPSF   = 1e-5f;
static constexpr float NEPSF  = (float)(1024 * 1e-5);

typedef __attribute__((ext_vector_type(8))) short short8;
typedef __attribute__((ext_vector_type(4))) float f32x4;

static __device__ __forceinline__ unsigned short f2bf(float f) {
    unsigned int u = __builtin_bit_cast(unsigned int, f);
    unsigned int r = (u + 0x7FFFu + ((u >> 16) & 1u)) >> 16;   // RNE
    return (unsigned short)r;
}
static __device__ __forceinline__ float bf2f(unsigned short h) {
    unsigned int u = ((unsigned int)h) << 16;
    return __builtin_bit_cast(float, u);
}

// ws layout (float offsets)
#define WS_ESUM    0         // 65536 (atomic-fallback target)
#define WS_CNTF    65536     // 1024  (atomic-fallback counts)
#define WS_DIFF    66560     // 1
#define WS_FLAGCNT 66561     // 1 (int)
#define WS_N       66562     // 1
#define WS_EE      66564     // 1024
#define WS_EMBEDT  67588     // 65536 (16B aligned)
#define WS_IDX     133124    // 131072 (int)
#define WS_FLAGLST 264196    // 131072 (int)
#define WS_BFRAG   395268    // 65536 floats = 256 KB (16B aligned)
#define WS_CNTPART 460804    // 32768 (NRANGE x 1024)
#define WS_PART    493572    // NRANGE x 65536 = 2097152 floats (16B aligned)
#define WS_NEED_BYTES ((size_t)(WS_PART + NRANGE * 65536) * 4)

// ---------------- prep: embedT, ee, hi/lo fragments of B' = -2*embed
__global__ void prep_kernel(const float* __restrict__ embed,
                            float* __restrict__ embedT,
                            float* __restrict__ ee,
                            uint4* __restrict__ BfragG) {
    int tid = blockIdx.x * 256 + threadIdx.x;      // 0..16383
    for (int i = 0; i < 4; ++i) {
        int id = i * 16384 + tid;
        int d = id >> 10, e = id & 1023;
        embedT[e * 64 + d] = embed[id];
    }
    if (tid < NEMB) {
        float s = 0.f;
        for (int d = 0; d < DIM; ++d) {
            float v = embed[d * 1024 + tid];
            s = fmaf(v, v, s);
        }
        ee[tid] = s;
    }
    int fid  = tid >> 6;            // 0..255
    int lane = tid & 63;
    int hl = fid & 1, kt = (fid >> 1) & 1, ct = fid >> 2;
    int col = ct * 16 + (lane & 15);
    int k0  = kt * 32 + (lane >> 4) * 8;
    unsigned short u[8];
    #pragma unroll
    for (int j = 0; j < 8; ++j) {
        float v = -2.0f * embed[(k0 + j) * 1024 + col];
        unsigned short h = f2bf(v);
        if (hl) h = f2bf(v - bf2f(h));
        u[j] = h;
    }
    uint4 wv;
    wv.x = (unsigned)u[0] | ((unsigned)u[1] << 16);
    wv.y = (unsigned)u[2] | ((unsigned)u[3] << 16);
    wv.z = (unsigned)u[4] | ((unsigned)u[5] << 16);
    wv.w = (unsigned)u[6] | ((unsigned)u[7] << 16);
    BfragG[fid * 64 + lane] = wv;
}

// ---------------- dist: hi/lo MFMA + best2 + quantize + diff (unchanged R7)
__global__ __launch_bounds__(256) void dist_kernel(
        const float* __restrict__ x, const uint4* __restrict__ BfragG,
        const float* __restrict__ ee, const float* __restrict__ embedT,
        float* __restrict__ out_q, float* __restrict__ out_ind,
        int* __restrict__ ws_idx, float* __restrict__ ws_diff,
        int* __restrict__ ws_flagcnt, int* __restrict__ ws_flaglist) {
    __shared__ uint4 Bs[2048];            // 32 KB
    __shared__ int   sIdx[128];
    __shared__ float red[4];

    const int t = threadIdx.x;
    const int w = t >> 6, lane = t & 63;
    const int quad = lane >> 4, wl = lane & 15;
    const int rbase = blockIdx.x * 128;

    short8 a_hi[2][2], a_lo[2][2];
    #pragma unroll
    for (int rt = 0; rt < 2; ++rt) {
        int row = rbase + w * 32 + rt * 16 + wl;
        #pragma unroll
        for (int kt = 0; kt < 2; ++kt) {
            const float* px = x + (size_t)row * 64 + kt * 32 + quad * 8;
            float4 v0 = *(const float4*)px;
            float4 v1 = *(const float4*)(px + 4);
            float vv[8] = {v0.x, v0.y, v0.z, v0.w, v1.x, v1.y, v1.z, v1.w};
            short8 ah, al;
            #pragma unroll
            for (int j = 0; j < 8; ++j) {
                unsigned short h = f2bf(vv[j]);
                ah[j] = (short)h;
                al[j] = (short)f2bf(vv[j] - bf2f(h));
            }
            a_hi[rt][kt] = ah; a_lo[rt][kt] = al;
        }
    }

    float b1[8], b2[8];
    int   i1[8];
    #pragma unroll
    for (int s = 0; s < 8; ++s) { b1[s] = 3.4e38f; b2[s] = 3.4e38f; i1[s] = 0; }

    const f32x4 zacc = {0.f, 0.f, 0.f, 0.f};

    for (int ch = 0; ch < 8; ++ch) {
        __syncthreads();
        const uint4* src = BfragG + ch * 2048;
        #pragma unroll
        for (int it = 0; it < 8; ++it) Bs[it * 256 + t] = src[it * 256 + t];
        __syncthreads();

        #pragma unroll
        for (int ctl = 0; ctl < 8; ++ctl) {
            const short8* bp = (const short8*)Bs;
            short8 bh0 = bp[(ctl * 4 + 0) * 64 + lane];
            short8 bl0 = bp[(ctl * 4 + 1) * 64 + lane];
            short8 bh1 = bp[(ctl * 4 + 2) * 64 + lane];
            short8 bl1 = bp[(ctl * 4 + 3) * 64 + lane];
            int col = ch * 128 + ctl * 16 + wl;
            float eec = ee[col];
            #pragma unroll
            for (int rt = 0; rt < 2; ++rt) {
                f32x4 c0 = __builtin_amdgcn_mfma_f32_16x16x32_bf16(a_lo[rt][0], bh0, zacc, 0, 0, 0);
                f32x4 c1 = __builtin_amdgcn_mfma_f32_16x16x32_bf16(a_lo[rt][1], bh1, zacc, 0, 0, 0);
                c0 = __builtin_amdgcn_mfma_f32_16x16x32_bf16(a_hi[rt][0], bl0, c0, 0, 0, 0);
                c1 = __builtin_amdgcn_mfma_f32_16x16x32_bf16(a_hi[rt][1], bl1, c1, 0, 0, 0);
                c0 = __builtin_amdgcn_mfma_f32_16x16x32_bf16(a_hi[rt][0], bh0, c0, 0, 0, 0);
                c1 = __builtin_amdgcn_mfma_f32_16x16x32_bf16(a_hi[rt][1], bh1, c1, 0, 0, 0);
                #pragma unroll
                for (int reg = 0; reg < 4; ++reg) {
                    float s = c0[reg] + c1[reg] + eec;          // v_add3_f32
                    int st = rt * 4 + reg;
                    bool lt = s < b1[st];
                    b2[st] = fminf(fmaxf(s, b1[st]), b2[st]);
                    i1[st] = lt ? col : i1[st];
                    b1[st] = fminf(s, b1[st]);
                }
            }
        }
    }

    for (int m = 1; m < 16; m <<= 1) {
        #pragma unroll
        for (int s = 0; s < 8; ++s) {
            float ob1 = __shfl_xor(b1[s], m);
            int   oi1 = __shfl_xor(i1[s], m);
            float ob2 = __shfl_xor(b2[s], m);
            if (ob1 < b1[s] || (ob1 == b1[s] && oi1 < i1[s])) {
                b2[s] = fminf(b1[s], ob2); b1[s] = ob1; i1[s] = oi1;
            } else {
                b2[s] = fminf(b2[s], ob1);
            }
        }
    }
    if (wl == 0) {
        #pragma unroll
        for (int s = 0; s < 8; ++s) {
            int rt = s >> 2, reg = s & 3;
            int rloc = w * 32 + rt * 16 + quad * 4 + reg;
            int row = rbase + rloc;
            sIdx[rloc] = i1[s];
            ws_idx[row] = i1[s];
            out_ind[row] = (float)i1[s];
            if (b2[s] - b1[s] < TAU) {
                int pos = atomicAdd(ws_flagcnt, 1);
                if (pos < FLAG_CAP) ws_flaglist[pos] = row;
            }
        }
    }
    __syncthreads();

    {
        int r = t >> 1, hh = t & 1;
        int e = sIdx[r];
        const float4* et = (const float4*)(embedT + e * 64 + hh * 32);
        const float4* xr = (const float4*)(x + (size_t)(rbase + r) * 64 + hh * 32);
        float4*       qo = (float4*)(out_q + (size_t)(rbase + r) * 64 + hh * 32);
        float dsum = 0.f;
        #pragma unroll
        for (int v = 0; v < 8; ++v) {
            float4 q4 = et[v];
            float4 x4 = xr[v];
            float dx = q4.x - x4.x, dy = q4.y - x4.y, dz = q4.z - x4.z, dw = q4.w - x4.w;
            float4 o;
            o.x = x4.x + dx; o.y = x4.y + dy; o.z = x4.z + dz; o.w = x4.w + dw;
            qo[v] = o;
            dsum += dx * dx + dy * dy + dz * dz + dw * dw;
        }
        for (int o2 = 32; o2 > 0; o2 >>= 1) dsum += __shfl_down(dsum, o2);
        if (lane == 0) red[w] = dsum;
        __syncthreads();
        if (t == 0) atomicAdd(ws_diff, red[0] + red[1] + red[2] + red[3]);
    }
}

// ---------------- recheck: tiled exact fp32 re-argmin (unchanged R7)
__global__ __launch_bounds__(256) void recheck_kernel(
        const float* __restrict__ x, const float* __restrict__ embed,
        const float* __restrict__ embedT, const float* __restrict__ ee,
        const int* __restrict__ flagcnt, const int* __restrict__ flaglist,
        int* __restrict__ ws_idx, float* __restrict__ out_ind,
        float* __restrict__ out_q, float* __restrict__ ws_diff) {
    __shared__ float sx[8][64];
    __shared__ float sff[8];
    __shared__ int   srow[8];
    __shared__ float sbd[256];
    __shared__ int   sbi[256];
    __shared__ int   schg[2];
    int t = threadIdx.x;
    int cnt = *flagcnt;
    if (cnt > FLAG_CAP) cnt = FLAG_CAP;
    int ntiles = (cnt + 7) >> 3;
    for (int tile = blockIdx.x; tile < ntiles; tile += gridDim.x) {
        int base = tile * 8;
        int nr = cnt - base; if (nr > 8) nr = 8;
        __syncthreads();
        if (t < nr) srow[t] = flaglist[base + t];
        __syncthreads();
        for (int l = t; l < nr * 64; l += 256)
            sx[l >> 6][l & 63] = x[(size_t)srow[l >> 6] * 64 + (l & 63)];
        __syncthreads();
        if (t < nr) {
            float ff = 0.f;
            for (int k = 0; k < 64; ++k) ff = fmaf(sx[t][k], sx[t][k], ff);
            sff[t] = ff;
        }
        float acc[8][4];
        #pragma unroll
        for (int r = 0; r < 8; ++r)
            #pragma unroll
            for (int j = 0; j < 4; ++j) acc[r][j] = 0.f;
        int c0 = t * 4;
        for (int k = 0; k < 64; ++k) {
            float4 e4 = *(const float4*)(embed + k * 1024 + c0);
            #pragma unroll
            for (int r = 0; r < 8; ++r) {
                float xk = sx[r][k];
                acc[r][0] = fmaf(xk, e4.x, acc[r][0]);
                acc[r][1] = fmaf(xk, e4.y, acc[r][1]);
                acc[r][2] = fmaf(xk, e4.z, acc[r][2]);
                acc[r][3] = fmaf(xk, e4.w, acc[r][3]);
            }
        }
        __syncthreads();
        for (int r = 0; r < nr; ++r) {
            int row = srow[r];
            float ff = sff[r];
            float bd = 3.4e38f; int bi = 0;
            #pragma unroll
            for (int j = 0; j < 4; ++j) {
                float d = (ff - 2.f * acc[r][j]) + ee[c0 + j];
                if (d < bd) { bd = d; bi = c0 + j; }
            }
            sbd[t] = bd; sbi[t] = bi;
            __syncthreads();
            for (int s = 128; s > 0; s >>= 1) {
                if (t < s) {
                    float od = sbd[t + s]; int oi = sbi[t + s];
                    if (od < sbd[t] || (od == sbd[t] && oi < sbi[t])) { sbd[t] = od; sbi[t] = oi; }
                }
                __syncthreads();
            }
            if (t == 0) {
                int ni = sbi[0], oi = ws_idx[row];
                schg[0] = ni; schg[1] = oi;
                if (ni != oi) { ws_idx[row] = ni; out_ind[row] = (float)ni; }
            }
            __syncthreads();
            int ni = schg[0], oi = schg[1];
            if (ni != oi && t < 64) {
                float xv = sx[r][t];
                float dn = embedT[ni * 64 + t] - xv;
                float dold = embedT[oi * 64 + t] - xv;
                out_q[(size_t)row * 64 + t] = xv + dn;
                float delta = dn * dn - dold * dold;
                for (int o = 32; o > 0; o >>= 1) delta += __shfl_down(delta, o);
                if (t == 0) atomicAdd(ws_diff, delta);
            }
            __syncthreads();
        }
    }
}

// ---------------- scatter: 32 ranges x 8 dim-octants; LDS hist [8 dims][1024 codes]
// Partial mode: plain coalesced stores to part[block][8192] — zero global atomics.
// Atomic mode (ws too small): R7-style atomic flush into esum/cntf.
__global__ __launch_bounds__(256) void scatter_kernel(
        const int* __restrict__ idx, const float* __restrict__ x,
        float* __restrict__ part_or_esum, float* __restrict__ cntp_or_cntf,
        int use_atomic) {
    __shared__ float shist[8192];         // [8 dims][1024 codes] = 32 KB
    __shared__ float scnt[1024];          // used by oct==0 blocks
    const int t = threadIdx.x;
    const int rb = blockIdx.x >> 3, oct = blockIdx.x & 7;      // 32 ranges x 8
    const int w = t >> 6, lane = t & 63;
    const int g = lane >> 3, d = lane & 7;                     // 8 rows x 8 dims

    for (int i = t; i < 8192; i += 256) shist[i] = 0.f;
    if (oct == 0) for (int i = t; i < 1024; i += 256) scnt[i] = 0.f;
    __syncthreads();

    const int row0 = rb * 4096 + w * 1024;
    int rcur = row0 + g;
    int e_n = idx[rcur];
    float x_n = x[(size_t)rcur * 64 + oct * 8 + d];
    for (int it = 0; it < 128; ++it) {                 // 128 x 8 rows per wave
        int e = e_n; float xv = x_n;
        int rnext = rcur + 8;
        if (it < 127) {                                // prefetch next iteration
            e_n = idx[rnext];
            x_n = x[(size_t)rnext * 64 + oct * 8 + d];
        }
        rcur = rnext;
        atomicAdd(&shist[d * 1024 + e], xv);
        if (oct == 0 && d == 0) atomicAdd(&scnt[e], 1.0f);
    }
    __syncthreads();

    if (!use_atomic) {
        float* dst = part_or_esum + (size_t)blockIdx.x * 8192;
        for (int cell = t; cell < 8192; cell += 256) dst[cell] = shist[cell];
        if (oct == 0) {
            float* cdst = cntp_or_cntf + rb * 1024;
            for (int i = t; i < 1024; i += 256) cdst[i] = scnt[i];
        }
    } else {
        for (int cell = t; cell < 8192; cell += 256) {
            float v = shist[cell];
            if (v != 0.f)
                atomicAdd(&part_or_esum[(oct * 8 + (cell >> 10)) * 1024 + (cell & 1023)], v);
        }
        if (oct == 0) {
            for (int i = t; i < 1024; i += 256) {
                float c = scnt[i];
                if (c != 0.f) atomicAdd(&cntp_or_cntf[i], c);
            }
        }
    }
}

// ---------------- finalize1: counts reduce + new_cluster_size, n, diff
__global__ __launch_bounds__(1024) void finalize1(
        const float* __restrict__ cluster_size, const float* __restrict__ cntp,
        int nrb, const float* __restrict__ ws_diff, float* __restrict__ out_diff,
        float* __restrict__ out_ncs, float* __restrict__ ws_n) {
    int t = threadIdx.x;
    float c = 0.f;
    for (int k = 0; k < nrb; ++k) c += cntp[k * 1024 + t];
    float ncs = DECAYF * cluster_size[t] + OMDF * c;
    out_ncs[t] = ncs;
    __shared__ float sred[16];
    float v = ncs;
    for (int o = 32; o > 0; o >>= 1) v += __shfl_down(v, o);
    if ((t & 63) == 0) sred[t >> 6] = v;
    __syncthreads();
    if (t == 0) {
        float n = 0.f;
        for (int i = 0; i < 16; ++i) n += sred[i];
        ws_n[0] = n;
        out_diff[0] = ws_diff[0] * (1.0f / 8388608.0f);   // /2^23 exact
    }
}

// ---------------- finalize2: partials reduce + new_embed_avg, new_embed
// part slab k covers j in [0,65536): slab index = k (partial mode, oct folded
// into j since part[block] slab ordering (rb*8+oct)*8192 + dd*1024 + e means
// j = oct*8192 + dd*1024 + e = global (dim*1024 + code) for slabs of fixed rb:
// thread j sums part[(k*8 + (j>>13))*8192 + (j&8191)] = part[k*65536 + j].
__global__ __launch_bounds__(256) void finalize2(
        const float* __restrict__ embed_avg, const float* __restrict__ part,
        int nrb, const float* __restrict__ out_ncs, const float* __restrict__ ws_n,
        float* __restrict__ out_nea, float* __restrict__ out_ne) {
    int j = blockIdx.x * 256 + threadIdx.x;      // < 65536 = dim*1024 + code
    float es = 0.f;
    for (int k = 0; k < nrb; ++k) es += part[(size_t)k * 65536 + j];
    float n = ws_n[0];
    float nea = DECAYF * embed_avg[j] + OMDF * es;
    out_nea[j] = nea;
    float ncs = out_ncs[j & 1023];
    float cs = (ncs + EPSF) / (n + NEPSF) * n;
    out_ne[j] = nea / cs;
}

extern "C" void kernel_launch(void* const* d_in, const int* in_sizes, int n_in,
                              void* d_out, int out_size, void* d_ws, size_t ws_size,
                              hipStream_t stream) {
    const float* x            = (const float*)d_in[0];
    const float* embed        = (const float*)d_in[1];
    const float* cluster_size = (const float*)d_in[2];
    const float* embed_avg    = (const float*)d_in[3];

    float* out = (float*)d_out;
    float* out_q    = out;                       // 8388608
    float* out_diff = out + 8388608;             // 1
    float* out_ind  = out + 8388609;             // 131072
    float* out_ncs  = out + 8519681;             // 1024
    float* out_nea  = out + 8520705;             // 65536
    float* out_ne   = out + 8586241;             // 65536

    float* ws = (float*)d_ws;
    float* ws_esum     = ws + WS_ESUM;
    float* ws_cntf     = ws + WS_CNTF;
    float* ws_diff     = ws + WS_DIFF;
    int*   ws_flagcnt  = (int*)(ws + WS_FLAGCNT);
    float* ws_n        = ws + WS_N;
    float* ws_ee       = ws + WS_EE;
    float* ws_embedT   = ws + WS_EMBEDT;
    int*   ws_idx      = (int*)(ws + WS_IDX);
    int*   ws_flaglist = (int*)(ws + WS_FLAGLST);
    uint4* ws_Bfrag    = (uint4*)(ws + WS_BFRAG);
    float* ws_cntpart  = ws + WS_CNTPART;
    float* ws_part     = ws + WS_PART;

    const int use_part = (ws_size >= WS_NEED_BYTES) ? 1 : 0;

    if (use_part) {
        hipMemsetAsync(ws + WS_DIFF, 0, 8, stream);          // diff + flagcnt only
    } else {
        hipMemsetAsync(d_ws, 0, (size_t)(WS_FLAGCNT + 1) * 4, stream);
    }

    prep_kernel<<<64, 256, 0, stream>>>(embed, ws_embedT, ws_ee, ws_Bfrag);
    dist_kernel<<<N_ROWS / 128, 256, 0, stream>>>(x, ws_Bfrag, ws_ee, ws_embedT,
                                                  out_q, out_ind, ws_idx, ws_diff,
                                                  ws_flagcnt, ws_flaglist);
    recheck_kernel<<<256, 256, 0, stream>>>(x, embed, ws_embedT, ws_ee,
                                            ws_flagcnt, ws_flaglist,
                                            ws_idx, out_ind, out_q, ws_diff);
    scatter_kernel<<<NRANGE * 8, 256, 0, stream>>>(
        ws_idx, x,
        use_part ? ws_part : ws_esum,
        use_part ? ws_cntpart : ws_cntf,
        use_part ? 0 : 1);
    finalize1<<<1, 1024, 0, stream>>>(cluster_size,
                                      use_part ? ws_cntpart : ws_cntf,
                                      use_part ? NRANGE : 1,
                                      ws_diff, out_diff, out_ncs, ws_n);
    finalize2<<<256, 256, 0, stream>>>(embed_avg,
                                       use_part ? ws_part : ws_esum,
                                       use_part ? NRANGE : 1,
                                       out_ncs, ws_n, out_nea, out_ne);
}